// Round 15
// baseline (206.173 us; speedup 1.0000x reference)
//
#include <hip/hip_runtime.h>
#include <hip/hip_bf16.h>

// B=2, L=4096, C=512, H=8, hd=64. f32 in/out; bf16 MFMA compute.
// v20: (a) flash dual-chunk windows: v19's 1568cyc/window vs ~460cyc issue
// = barrier-lockstep too fine at 32 keys/barrier. Now 64 keys/window
// (4x8KB LDS, stage 2 chunks, process 2 with deferred-PV; QK(2w+1) is
// independent work that fills exp2/PV chain latency; barriers 128->64).
// (b) qkv_rope q/k epilogue was 32x 2B scatter-stores/thread; now routed
// through LDS ([128][72] pos-major tile) and emitted FRAGMENT-PACKED with
// 16B coalesced stores -- Q's B-frag packing formula is IDENTICAL to K's
// A-frag formula, one emit loop serves both; flash Q-read becomes 4
// contiguous 1KB wave-loads. All other kernels unchanged from v17-19.

typedef __attribute__((ext_vector_type(8)))  short short8;    // 8 bf16
typedef __attribute__((ext_vector_type(4)))  short short4v;   // 4 bf16
typedef __attribute__((ext_vector_type(4)))  float floatx4;   // 16x16 C/D
typedef __attribute__((ext_vector_type(16))) float floatx16;  // 32x32 C/D

#define MFMA(a, b, c)   __builtin_amdgcn_mfma_f32_16x16x32_bf16((a), (b), (c), 0, 0, 0)
#define MFMA32(a, b, c) __builtin_amdgcn_mfma_f32_32x32x16_bf16((a), (b), (c), 0, 0, 0)

__device__ __forceinline__ float fast_exp2(float x) {
#if __has_builtin(__builtin_amdgcn_exp2f)
    return __builtin_amdgcn_exp2f(x);
#else
    float r; asm("v_exp_f32 %0, %1" : "=v"(r) : "v"(x)); return r;
#endif
}

__device__ __forceinline__ unsigned short f2bf(float f) {
    unsigned int u = __builtin_bit_cast(unsigned int, f);
    return (unsigned short)((u + 0x7fffu + ((u >> 16) & 1u)) >> 16);  // RTNE
}
__device__ __forceinline__ unsigned int pack2(float lo, float hi) {
    __hip_bfloat162 h = __float22bfloat162_rn(make_float2(lo, hi));  // 1 instr
    unsigned int r;
    __builtin_memcpy(&r, &h, 4);
    return r;
}

// ---------------------------------------------------------------------------
// f32 (rows, 512) row-major -> bf16 FRAGMENT-PACKED (16x16x32 A/B layout).
// ---------------------------------------------------------------------------
__global__ __launch_bounds__(256) void conv_pack(
    const float* __restrict__ src, ushort* __restrict__ dst, int n8)
{
    int i = blockIdx.x * blockDim.x + threadIdx.x;
    if (i >= n8) return;
    const int row = i >> 6, col0 = (i & 63) * 8;
    const float4* s = (const float4*)(src + (size_t)row * 512 + col0);
    float4 a = s[0], b = s[1];
    uint4 r = { pack2(a.x, a.y), pack2(a.z, a.w), pack2(b.x, b.y), pack2(b.z, b.w) };
    const int l = (row & 15) + 16 * ((col0 >> 3) & 3);
    const size_t off = (size_t)(row >> 4) * 8192 + (size_t)(col0 >> 5) * 512 + l * 8;
    *(uint4*)(dst + off) = r;
}

// RoPE LUT: lut[pos*32+j] = {cos, sin}(pos * 10000^(-j/32))
__global__ __launch_bounds__(256) void build_rope(float2* __restrict__ lut) {
    int i = blockIdx.x * 256 + threadIdx.x;   // 131072 entries
    int pos = i >> 5, j = i & 31;
    float invf = exp2f(-0.41524101186f * (float)j);
    float s, c;
    sincosf((float)pos * invf, &s, &c);
    lut[i] = make_float2(c, s);
}

// ---------------------------------------------------------------------------
// qkv = xb @ wb.T + b for G heads from h0; RoPE q,k (LUT); q pre-scaled by
// 0.125*log2e. xb/wb fragment-packed (1KB wave-loads).
// q AND k emitted FRAGMENT-PACKED via an LDS [128 pos][72] tile:
//   idx(pos,d) = (pos>>5)*2048 + (d>>4)*512 + ((pos&31)+32*((d>>3)&1))*8 + (d&7)
// (q = flash B-frag, k = flash A-frag -- same formula). v emitted kappa-
// permuted packed via LDS [64 d][136] tile (unchanged). Wave 32(M) x 64(N).
// ---------------------------------------------------------------------------
__global__ __launch_bounds__(256) void qkv_rope(
    const ushort* __restrict__ xb,    // packed (8192, 512) bf16
    const ushort* __restrict__ wb,    // packed (1536, 512) bf16
    const float* __restrict__ bias,   // (1536,) f32
    const float2* __restrict__ lut,   // (4096, 32)
    ushort* __restrict__ q, ushort* __restrict__ k, ushort* __restrict__ vt,
    int G, int h0)
{
    __shared__ __align__(16) ushort tl[9216];   // 18432 B; qk view [128][72], v view [64][136]
    const int w_id = threadIdx.x >> 6;
    const int lane = threadIdx.x & 63;
    const int lr = lane & 15, quad = lane >> 4;
    const int m0 = blockIdx.x * 128 + w_id * 32;
    const int sec = blockIdx.y / G, hl = blockIdx.y % G;
    const int wc0 = sec * 512 + (h0 + hl) * 64;

    floatx4 acc[2][4] = {};
    const ushort* xa = xb + (size_t)(m0 >> 4) * 8192 + lane * 8;
    const ushort* wbase = wb + (size_t)(wc0 >> 4) * 8192 + lane * 8;
    for (int kk = 0; kk < 16; ++kk) {
        short8 a0 = *(const short8*)(xa + kk * 512);
        short8 a1 = *(const short8*)(xa + 8192 + kk * 512);
#pragma unroll
        for (int nt = 0; nt < 4; ++nt) {
            short8 b = *(const short8*)(wbase + (size_t)nt * 8192 + kk * 512);
            acc[0][nt] = MFMA(a0, b, acc[0][nt]);
            acc[1][nt] = MFMA(a1, b, acc[1][nt]);
        }
    }

    const int m0b = blockIdx.x * 128;
    const int bb = m0b >> 12;
    const int pos0 = m0b & 4095;
    const size_t bhl = (size_t)(bb * G + hl);

    if (sec < 2) {
        // RoPE into LDS tile [pos][d] (stride 72 shorts = 144B, 16B-aligned rows)
#pragma unroll
        for (int mt = 0; mt < 2; ++mt)
#pragma unroll
            for (int nt = 0; nt < 4; ++nt) {
                const int d = nt * 16 + lr;
                const float bv = bias[wc0 + d];
#pragma unroll
                for (int r = 0; r < 4; ++r) {
                    const int pl = w_id * 32 + mt * 16 + quad * 4 + r;
                    const int pos = pos0 + pl;
                    float val = acc[mt][nt][r] + bv;
                    float partner = __shfl_xor(val, 1);
                    float2 cs = lut[(pos << 5) | (d & 31)];
                    float rh = (d & 1) ? partner : -partner;   // rotate_half
                    float rv = val * cs.x + rh * cs.y;
                    if (sec == 0) rv *= 0.18033688011112042f;  // 0.125*log2(e)
                    tl[pl * 72 + d] = f2bf(rv);
                }
            }
        __syncthreads();
        // fragment-packed emit, 16B coalesced stores (4 per thread)
        ushort* dst = ((sec == 0) ? q : k) + bhl * 262144 + (pos0 >> 5) * 2048;
#pragma unroll
        for (int i = 0; i < 4; ++i) {
            const int combo = i * 4 + w_id;       // c4*4 + ks
            const int c4 = combo >> 2, ks = combo & 3;
            short8 vv = *(const short8*)&tl[(c4 * 32 + (lane & 31)) * 72
                                            + ks * 16 + (lane >> 5) * 8];
            *(short8*)(dst + c4 * 2048 + ks * 512 + lane * 8) = vv;
        }
    } else {
        // v: stage tile [64 d][136 pos] in LDS; emit kappa-permuted packed
        // fragments as 1KB-coalesced stores (unchanged from v17).
#pragma unroll
        for (int mt = 0; mt < 2; ++mt)
#pragma unroll
            for (int nt = 0; nt < 4; ++nt) {
                const int d = nt * 16 + lr;
                const float bv = bias[wc0 + d];
                short4v v4;
#pragma unroll
                for (int r = 0; r < 4; ++r)
                    v4[r] = (short)f2bf(acc[mt][nt][r] + bv);
                *(short4v*)&tl[d * 136 + w_id * 32 + mt * 16 + quad * 4] = v4;
            }
        __syncthreads();
        const int c0g = pos0 >> 5;            // first chunk of this tile
        const int gid = w_id;
        const int l = lane;
        const int h = l >> 5;
        ushort* vb = vt + bhl * 262144 + l * 8;
#pragma unroll
        for (int i = 0; i < 4; ++i) {
            const int combo = i * 4 + gid;    // c4*4 + dt*2 + s
            const int c4 = combo >> 2, dt = (combo >> 1) & 1, s = combo & 1;
            const int d = dt * 32 + (l & 31);
            const int colbase = c4 * 32 + s * 16 + 4 * h;
            short4v a = *(const short4v*)&tl[d * 136 + colbase];        // e=0..3
            short4v b = *(const short4v*)&tl[d * 136 + colbase + 8];    // e=4..7
            short8 vv = __builtin_shufflevector(a, b, 0, 1, 2, 3, 4, 5, 6, 7);
            *(short8*)(vb + (size_t)(c0g + c4) * 2048 + dt * 1024 + s * 512) = vv;
        }
    }
}

// ---------------------------------------------------------------------------
// Flash v20 (block-cooperative, dual-chunk windows, deferred PV). Block =
// 4 waves x 32 queries = 128 queries over ALL 4096 keys. 64-key windows:
// 4x8KB LDS (2 pairs), stage 2 chunks/window, 1 barrier/window. Pipeline:
// glb_load(2w+2,2w+3) ; ds_read(2w,2w+1) ; PV(2w-1) ; QK(2w) ; QK(2w+1) ;
// smax(2w) ; PV(2w) ; smax(2w+1) ; ds_write ; barrier. pb/vp carried.
// ---------------------------------------------------------------------------
__global__ __launch_bounds__(256, 2) void flash_attn(
    const ushort* __restrict__ q, const ushort* __restrict__ k,
    const ushort* __restrict__ vt, ushort* __restrict__ o,
    int G, int h0)
{
    __shared__ __align__(16) ushort kv[4][4096];   // 32 KB
    const int w_id = threadIdx.x >> 6;
    const int lane = threadIdx.x & 63;
    const int ln31 = lane & 31, h = lane >> 5;
    const int nbh = 2 * G;
    const int bhl = blockIdx.x % nbh;
    const int qt = blockIdx.x / nbh;              // 0..31
    const int b_ = bhl / G, hl = bhl % G;
    const int q0 = qt * 128 + w_id * 32;

    const ushort* qp = q + (size_t)bhl * 262144;
    const ushort* kp = k + (size_t)bhl * 262144;
    const ushort* vp_ = vt + (size_t)bhl * 262144;
    const int hcol = (h0 + hl) * 64;
    ushort* opp = o + (size_t)(((b_ << 12) + q0) >> 4) * 8192 + (hcol >> 5) * 512;

    // staging: waves 0,1 stage K halves; waves 2,3 stage V halves
    const ushort* stsrc = ((w_id < 2) ? kp : vp_) + (w_id & 1) * 1024 + lane * 8;
    const int stdst = w_id * 1024 + lane * 8;

    // Q B-frags from PACKED q: 4 contiguous loads
    short8 qf[4];
    {
        const ushort* qb = qp + (q0 >> 5) * 2048 + lane * 8;
        qf[0] = *(const short8*)(qb);
        qf[1] = *(const short8*)(qb + 512);
        qf[2] = *(const short8*)(qb + 1024);
        qf[3] = *(const short8*)(qb + 1536);
    }

    floatx16 oacc[2] = {};     // [dtile]: O[d=dtile*32+row(reg)][q0+ln31]
    float lsum = 0.f;
    short8 pb0, pb1;           // P frags (carried)
    short8 vp0, vp1, vp2, vp3; // V frags of previous chunk (carried)

    auto ldfr = [&](const ushort* b, short8& f0, short8& f1, short8& f2, short8& f3) {
        f0 = *(const short8*)(b);
        f1 = *(const short8*)(b + 512);
        f2 = *(const short8*)(b + 1024);
        f3 = *(const short8*)(b + 1536);
    };
    auto qk32 = [&](short8 a0, short8 a1, short8 a2, short8 a3) {
        floatx16 s = {};
        s = MFMA32(a0, qf[0], s);
        s = MFMA32(a1, qf[1], s);
        s = MFMA32(a2, qf[2], s);
        s = MFMA32(a3, qf[3], s);
        return s;
    };
    auto smax = [&](const floatx16& s) {
        float p[16];
#pragma unroll
        for (int r = 0; r < 16; ++r) p[r] = fast_exp2(s[r]);
        float t0 = (p[0] + p[1]) + (p[2] + p[3]);
        float t1 = (p[4] + p[5]) + (p[6] + p[7]);
        float t2 = (p[8] + p[9]) + (p[10] + p[11]);
        float t3 = (p[12] + p[13]) + (p[14] + p[15]);
        lsum += (t0 + t1) + (t2 + t3);
        uint4 u0 = { pack2(p[0], p[1]), pack2(p[2], p[3]),
                     pack2(p[4], p[5]), pack2(p[6], p[7]) };
        uint4 u1 = { pack2(p[8], p[9]), pack2(p[10], p[11]),
                     pack2(p[12], p[13]), pack2(p[14], p[15]) };
        pb0 = __builtin_bit_cast(short8, u0);   // keys kappa(0..15)
        pb1 = __builtin_bit_cast(short8, u1);   // keys kappa(16..31)
    };
    auto pv = [&](short8 a0, short8 a1, short8 a2, short8 a3) {
        oacc[0] = MFMA32(a0, pb0, oacc[0]);
        oacc[0] = MFMA32(a1, pb1, oacc[0]);
        oacc[1] = MFMA32(a2, pb0, oacc[1]);
        oacc[1] = MFMA32(a3, pb1, oacc[1]);
    };

    // prologue: stage chunks 0,1 into kv[0],kv[1]
    {
        short8 t0 = *(const short8*)(stsrc);
        short8 t1 = *(const short8*)(stsrc + 512);
        short8 t2 = *(const short8*)(stsrc + 2048);
        short8 t3 = *(const short8*)(stsrc + 2048 + 512);
        *(short8*)(&kv[0][stdst]) = t0;
        *(short8*)(&kv[0][stdst + 512]) = t1;
        *(short8*)(&kv[1][stdst]) = t2;
        *(short8*)(&kv[1][stdst + 512]) = t3;
    }
    __syncthreads();

    // window 0: chunks 0,1 (no PV from previous); stage 2,3
    {
        const ushort* src = stsrc + 2 * 2048;
        short8 t0 = *(const short8*)(src);
        short8 t1 = *(const short8*)(src + 512);
        short8 t2 = *(const short8*)(src + 2048);
        short8 t3 = *(const short8*)(src + 2048 + 512);
        short8 ka0, ka1, ka2, ka3, kb0, kb1, kb2, kb3, va0, va1, va2, va3;
        ldfr(&kv[0][lane * 8], ka0, ka1, ka2, ka3);
        ldfr(&kv[0][lane * 8 + 2048], va0, va1, va2, va3);
        ldfr(&kv[1][lane * 8], kb0, kb1, kb2, kb3);
        floatx16 s0 = qk32(ka0, ka1, ka2, ka3);
        floatx16 s1 = qk32(kb0, kb1, kb2, kb3);
        smax(s0);                                // pb = chunk 0
        pv(va0, va1, va2, va3);                  // PV(0)
        ldfr(&kv[1][lane * 8 + 2048], vp0, vp1, vp2, vp3);   // V(1) carried
        smax(s1);                                // pb = chunk 1
        *(short8*)(&kv[2][stdst]) = t0;
        *(short8*)(&kv[2][stdst + 512]) = t1;
        *(short8*)(&kv[3][stdst]) = t2;
        *(short8*)(&kv[3][stdst + 512]) = t3;
        __syncthreads();
    }

    // steady state: windows 1..62 (chunks 2w,2w+1; stage 2w+2,2w+3)
    for (int w = 1; w < 63; ++w) {
        const int pr = (w & 1) * 2;
        const ushort* src = stsrc + (2 * w + 2) * 2048;
        short8 t0 = *(const short8*)(src);
        short8 t1 = *(const short8*)(src + 512);
        short8 t2 = *(const short8*)(src + 2048);
        short8 t3 = *(const short8*)(src + 2048 + 512);
        short8 ka0, ka1, ka2, ka3, kb0, kb1, kb2, kb3, va0, va1, va2, va3;
        ldfr(&kv[pr][lane * 8], ka0, ka1, ka2, ka3);
        ldfr(&kv[pr][lane * 8 + 2048], va0, va1, va2, va3);
        ldfr(&kv[pr + 1][lane * 8], kb0, kb1, kb2, kb3);
        pv(vp0, vp1, vp2, vp3);                  // PV(2w-1), carried pb
        floatx16 s0 = qk32(ka0, ka1, ka2, ka3);
        floatx16 s1 = qk32(kb0, kb1, kb2, kb3);  // independent work
        smax(s0);                                // pb = chunk 2w
        pv(va0, va1, va2, va3);                  // PV(2w)
        ldfr(&kv[pr + 1][lane * 8 + 2048], vp0, vp1, vp2, vp3);  // V(2w+1)
        smax(s1);                                // pb = chunk 2w+1
        const int op = pr ^ 2;
        *(short8*)(&kv[op][stdst]) = t0;
        *(short8*)(&kv[op][stdst + 512]) = t1;
        *(short8*)(&kv[op + 1][stdst]) = t2;
        *(short8*)(&kv[op + 1][stdst + 512]) = t3;
        __syncthreads();
    }

    // final window: chunks 126,127 in kv[2],kv[3]
    {
        short8 ka0, ka1, ka2, ka3, kb0, kb1, kb2, kb3;
        short8 va0, va1, va2, va3, vb0, vb1, vb2, vb3;
        ldfr(&kv[2][lane * 8], ka0, ka1, ka2, ka3);
        ldfr(&kv[2][lane * 8 + 2048], va0, va1, va2, va3);
        ldfr(&kv[3][lane * 8], kb0, kb1, kb2, kb3);
        ldfr(&kv[3][lane * 8 + 2048], vb0, vb1, vb2, vb3);
        pv(vp0, vp1, vp2, vp3);                  // PV(125)
        floatx16 s0 = qk32(ka0, ka1, ka2, ka3);
        floatx16 s1 = qk32(kb0, kb1, kb2, kb3);
        smax(s0);
        pv(va0, va1, va2, va3);                  // PV(126)
        smax(s1);
        pv(vb0, vb1, vb2, vb3);                  // PV(127)
    }

    // halves hold disjoint key subsets for the same query
    lsum += __shfl_xor(lsum, 32);

    // private epilogue: normalize and store packed o
    const float inv = 1.0f / lsum;
#pragma unroll
    for (int dt = 0; dt < 2; ++dt)
#pragma unroll
        for (int g = 0; g < 4; ++g) {
            float v0 = oacc[dt][4 * g + 0] * inv;
            float v1 = oacc[dt][4 * g + 1] * inv;
            float v2 = oacc[dt][4 * g + 2] * inv;
            float v3 = oacc[dt][4 * g + 3] * inv;
            uint2 u = { pack2(v0, v1), pack2(v2, v3) };
            // packed o store: row = q0+ln31, col = hcol + dt*32 + 8g + 4h
            *(uint2*)(opp + (size_t)(ln31 >> 4) * 8192 + dt * 512
                      + ((ln31 & 15) + 16 * g) * 8 + 4 * h) = u;
        }
}

// ---------------------------------------------------------------------------
// out(f32) = o(bf16, packed) @ wb.T(packed) + proj_b. Wave 32(M) x 64(N).
// ---------------------------------------------------------------------------
__global__ __launch_bounds__(256) void proj_gemm(
    const ushort* __restrict__ o,      // packed (8192, 512) bf16
    const ushort* __restrict__ wb,     // packed (512, 512) bf16
    const float* __restrict__ bias,    // (512,) f32
    float* __restrict__ out)           // (8192, 512) f32
{
    const int w_id = threadIdx.x >> 6;
    const int lane = threadIdx.x & 63;
    const int lr = lane & 15, quad = lane >> 4;
    const int m0 = blockIdx.x * 128 + w_id * 32;
    const int n0 = blockIdx.y * 64;

    floatx4 acc[2][4] = {};
    const ushort* oa = o + (size_t)(m0 >> 4) * 8192 + lane * 8;
    const ushort* wbase = wb + (size_t)(n0 >> 4) * 8192 + lane * 8;
    for (int kk = 0; kk < 16; ++kk) {
        short8 a0 = *(const short8*)(oa + kk * 512);
        short8 a1 = *(const short8*)(oa + 8192 + kk * 512);
#pragma unroll
        for (int nt = 0; nt < 4; ++nt) {
            short8 b = *(const short8*)(wbase + (size_t)nt * 8192 + kk * 512);
            acc[0][nt] = MFMA(a0, b, acc[0][nt]);
            acc[1][nt] = MFMA(a1, b, acc[1][nt]);
        }
    }
#pragma unroll
    for (int mt = 0; mt < 2; ++mt)
#pragma unroll
        for (int nt = 0; nt < 4; ++nt) {
            const int n = n0 + nt * 16 + lr;
            const float bv = bias[n];
#pragma unroll
            for (int r = 0; r < 4; ++r)
                out[(size_t)(m0 + mt * 16 + quad * 4 + r) * 512 + n] = acc[mt][nt][r] + bv;
        }
}

extern "C" void kernel_launch(void* const* d_in, const int* in_sizes, int n_in,
                              void* d_out, int out_size, void* d_ws, size_t ws_size,
                              hipStream_t stream)
{
    const float* x      = (const float*)d_in[0];
    const float* qkv_w  = (const float*)d_in[1];
    const float* qkv_b  = (const float*)d_in[2];
    const float* proj_w = (const float*)d_in[3];
    const float* proj_b = (const float*)d_in[4];
    float* out = (float*)d_out;

    const size_t MB = (size_t)1 << 20;
    ushort* base = (ushort*)d_ws;
    int G;
    ushort *xb, *o, *wb, *pwb, *q, *k, *vt;
    if (ws_size >= 34 * MB) {
        // G=8: single group -> o aliases xb (xb dead before flash runs)
        G = 8;
        xb = base; o = base;                 // 8 MiB shared
        wb  = base + 4194304;                // 1.5 MiB
        pwb = wb + 786432;                   // 0.5 MiB
        q   = pwb + 262144;
        k   = q + (size_t)G * 524288;
        vt  = k + (size_t)G * 524288;
    } else {
        G = (ws_size >= 30 * MB) ? 4 : (ws_size >= 24 * MB) ? 2 : 1;
        xb  = base;
        o   = base + 4194304;
        wb  = o + 4194304;
        pwb = wb + 786432;
        q   = pwb + 262144;
        k   = q + (size_t)G * 524288;
        vt  = k + (size_t)G * 524288;
    }

    // RoPE LUT in the head of d_out (1 MB) — dead before proj writes.
    float2* lut = (float2*)d_out;
    build_rope<<<512, 256, 0, stream>>>(lut);

    conv_pack<<<2048, 256, 0, stream>>>(x, xb, 524288);
    conv_pack<<<384, 256, 0, stream>>>(qkv_w, wb, 98304);
    conv_pack<<<128, 256, 0, stream>>>(proj_w, pwb, 32768);

    for (int h0 = 0; h0 < 8; h0 += G) {
        qkv_rope<<<dim3(64, 3 * G), 256, 0, stream>>>(xb, wb, qkv_b, lut, q, k, vt, G, h0);
        flash_attn<<<32 * 2 * G, 256, 0, stream>>>(q, k, vt, o, G, h0);
    }
    proj_gemm<<<dim3(64, 8), 256, 0, stream>>>(o, pwb, proj_b, out);
}